// Round 5
// baseline (292.943 us; speedup 1.0000x reference)
//
#include <hip/hip_runtime.h>
#include <hip/hip_bf16.h>

#define TOKENS 8192
#define IN_F   4096
#define OUT_F  4096

// GEMM geometry: 256x256 tile, BK=64, 8 waves (2M x 4N), 512 threads
#define BM 256
#define BN 256
#define BK 64
#define NT (IN_F / BK)   // 64 K-tiles

typedef float  f32x4  __attribute__((ext_vector_type(4)));
typedef __bf16 bf16x8 __attribute__((ext_vector_type(8)));

#define BARRIER() asm volatile("s_barrier" ::: "memory")
#define VMCNT4()  asm volatile("s_waitcnt vmcnt(4)" ::: "memory")
#define VMCNT0()  asm volatile("s_waitcnt vmcnt(0)" ::: "memory")
#define LGKM0()   asm volatile("s_waitcnt lgkmcnt(0)" ::: "memory")

// fp32 -> bf16 round-to-nearest-even
__device__ __forceinline__ unsigned short f2bf(float f) {
  unsigned u = __builtin_bit_cast(unsigned, f);
  u += 0x7FFFu + ((u >> 16) & 1u);
  return (unsigned short)(u >> 16);
}

__device__ __forceinline__ void gload_lds16(const void* g, void* l) {
  __builtin_amdgcn_global_load_lds(
      (const __attribute__((address_space(1))) void*)g,
      (__attribute__((address_space(3))) void*)l, 16, 0, 0);
}

// ---------------------------------------------------------------------------
// Kernel 1: W = dequant_int4(base_weight)*scale + CSR ortho  ->  bf16 [OUT_F][IN_F]
// ---------------------------------------------------------------------------
__global__ __launch_bounds__(256) void prep_w(
    const int* __restrict__ bw, const float* __restrict__ scales,
    const float* __restrict__ vals, const int* __restrict__ cols,
    const int* __restrict__ rptr, unsigned short* __restrict__ W) {
  __shared__ float row[IN_F];
  const int n = blockIdx.x;
  const float s = scales[n];
  const int* bwr = bw + (size_t)n * (IN_F / 2);
#pragma unroll
  for (int it = 0; it < (IN_F / 2) / 256; ++it) {
    int j = it * 256 + threadIdx.x;
    int p = bwr[j];
    int lo = p & 15;        lo = (lo >= 8) ? lo - 16 : lo;
    int hi = (p >> 4) & 15; hi = (hi >= 8) ? hi - 16 : hi;
    row[2 * j]     = (float)lo * s;
    row[2 * j + 1] = (float)hi * s;
  }
  __syncthreads();
  const int b = rptr[n], e = rptr[n + 1];
  for (int t = b + (int)threadIdx.x; t < e; t += 256)
    atomicAdd(&row[cols[t]], vals[t]);
  __syncthreads();
  unsigned short* Wr = W + (size_t)n * IN_F;
#pragma unroll
  for (int it = 0; it < IN_F / 256; ++it) {
    int j = it * 256 + threadIdx.x;
    Wr[j] = f2bf(row[j]);
  }
}

// ---------------------------------------------------------------------------
// Kernel 2: X fp32 -> bf16
// ---------------------------------------------------------------------------
__global__ __launch_bounds__(256) void cvt_x(const float4* __restrict__ x,
                                             ushort4* __restrict__ xb, int nvec) {
  int i = blockIdx.x * blockDim.x + threadIdx.x;
  int stride = gridDim.x * blockDim.x;
  for (; i < nvec; i += stride) {
    float4 v = x[i];
    ushort4 o;
    o.x = f2bf(v.x); o.y = f2bf(v.y); o.z = f2bf(v.z); o.w = f2bf(v.w);
    xb[i] = o;
  }
}

// ---------------------------------------------------------------------------
// Kernel 3: 256x256 8-phase GEMM. C[M,N] = A[M,K] x B[N,K]^T, bf16 in, f32 out.
//
// LDS tile layout (per 256x64 operand tile, 32 KB):
//   byte(r,k) = (k>>5)*16384 + (r>>4)*1024 + (r&15)*64 + (k&31)*2
//   then byte ^= ((byte>>9)&1)<<5        (st_16x32 XOR swizzle)
// global_load_lds writes LINEAR dest (thread t -> bytes t*16); the global
// source address is the inverse-swizzled element, so LDS holds the swizzled
// layout and readers apply the same XOR. (both-sides rule, m104/m201)
//
// Schedule per K-tile (4 phases): (q0,k0)(q1,k0)(q0,k1)(q1,k1); each phase
// stages one 16KB unit of tile t+1 into the other buffer; vmcnt(4) only at
// even-phase boundaries (the 4 loads needed next are always the oldest 4
// of <=8 outstanding).
// ---------------------------------------------------------------------------
__global__ __launch_bounds__(512, 2) void gemm_bf16_8ph(
    const unsigned short* __restrict__ A,   // [TOKENS][IN_F] bf16
    const unsigned short* __restrict__ B,   // [OUT_F][IN_F] bf16
    float* __restrict__ C) {                // [TOKENS][OUT_F] f32
  __shared__ __align__(16) char lds[131072];  // 2 buf x (A 32K + B 32K)

  const int nbn = OUT_F / BN;               // 16
  const int cpx = ((TOKENS / BM) * nbn) >> 3;  // 512/8 = 64
  const int bid = blockIdx.x;
  const int swz = (bid & 7) * cpx + (bid >> 3);
  const int tm = swz / nbn, tn = swz % nbn;
  const long m0 = (long)tm * BM;
  const long n0 = (long)tn * BN;

  const int tid  = threadIdx.x;
  const int lane = tid & 63;
  const int wid  = tid >> 6;                // 0..7
  const int wr   = wid >> 2;                // 0..1
  const int wc   = wid & 3;                 // 0..3

  // ---- staging precompute: linear LDS byte p -> logical (r, k) (inverse swz)
  const int p0 = tid * 16;
  const int p1 = tid * 16 + 8192;
  const int lin0 = p0 ^ (((p0 >> 9) & 1) << 5);
  const int lin1 = p1 ^ (((p1 >> 9) & 1) << 5);
  const int r0 = (((p0 >> 10) & 15) << 4) | ((lin0 >> 6) & 15);
  const int r1 = (((p1 >> 10) & 15) << 4) | ((lin1 >> 6) & 15);
  const int k0 = (lin0 >> 1) & 31;
  const int k1 = (lin1 >> 1) & 31;

  const unsigned short* Abase = A + m0 * IN_F;
  const unsigned short* Bbase = B + n0 * IN_F;

  // ---- reader lane offset (with XOR swizzle; bit9 == bit3 of (lane&15))
  int laneoff = ((lane & 15) << 6) | ((lane >> 4) << 4);
  laneoff ^= ((laneoff >> 9) & 1) << 5;

#define STAGE_A(nb, kt, h)                                                    \
  do {                                                                        \
    gload_lds16(Abase + (size_t)r0 * IN_F + (kt) * 64 + (h) * 32 + k0,        \
                lds + (nb) * 65536 + (h) * 16384 + p0);                       \
    gload_lds16(Abase + (size_t)r1 * IN_F + (kt) * 64 + (h) * 32 + k1,        \
                lds + (nb) * 65536 + (h) * 16384 + p1);                       \
  } while (0)
#define STAGE_B(nb, kt, h)                                                    \
  do {                                                                        \
    gload_lds16(Bbase + (size_t)r0 * IN_F + (kt) * 64 + (h) * 32 + k0,        \
                lds + (nb) * 65536 + 32768 + (h) * 16384 + p0);               \
    gload_lds16(Bbase + (size_t)r1 * IN_F + (kt) * 64 + (h) * 32 + k1,        \
                lds + (nb) * 65536 + 32768 + (h) * 16384 + p1);               \
  } while (0)

  f32x4 acc[8][4];
#pragma unroll
  for (int i = 0; i < 8; ++i)
#pragma unroll
    for (int j = 0; j < 4; ++j) acc[i][j] = (f32x4)0.0f;

  // ---- prologue: stage tile 0 fully into buf 0
  STAGE_A(0, 0, 0);
  STAGE_B(0, 0, 0);
  STAGE_A(0, 0, 1);
  STAGE_B(0, 0, 1);
  VMCNT0();
  BARRIER();

  for (int t = 0; t < NT; ++t) {
    const int b  = t & 1;
    const int nb = b ^ 1;
    const char* bufA = lds + b * 65536;
    const char* bufB = lds + b * 65536 + 32768;
    const bool pf = (t + 1 < NT);
    bf16x8 av[4], bv[4];

    // ================= P1: quad 0, k-half 0 =================
#pragma unroll
    for (int i = 0; i < 4; ++i)
      av[i] = *(const bf16x8*)(bufA + (wr * 8 + i) * 1024 + laneoff);
#pragma unroll
    for (int j = 0; j < 4; ++j)
      bv[j] = *(const bf16x8*)(bufB + (wc * 4 + j) * 1024 + laneoff);
    if (pf) STAGE_A(nb, t + 1, 0);
    BARRIER();
    LGKM0();
    __builtin_amdgcn_s_setprio(1);
#pragma unroll
    for (int i = 0; i < 4; ++i)
#pragma unroll
      for (int j = 0; j < 4; ++j)
        acc[i][j] = __builtin_amdgcn_mfma_f32_16x16x32_bf16(av[i], bv[j], acc[i][j], 0, 0, 0);
    __builtin_amdgcn_s_setprio(0);
    BARRIER();

    // ================= P2: quad 1, k-half 0 =================
#pragma unroll
    for (int i = 0; i < 4; ++i)
      av[i] = *(const bf16x8*)(bufA + (wr * 8 + 4 + i) * 1024 + laneoff);
    if (pf) STAGE_B(nb, t + 1, 0);
    BARRIER();
    LGKM0();
    __builtin_amdgcn_s_setprio(1);
#pragma unroll
    for (int i = 0; i < 4; ++i)
#pragma unroll
      for (int j = 0; j < 4; ++j)
        acc[4 + i][j] = __builtin_amdgcn_mfma_f32_16x16x32_bf16(av[i], bv[j], acc[4 + i][j], 0, 0, 0);
    __builtin_amdgcn_s_setprio(0);
    if (pf) { VMCNT4(); } else { VMCNT0(); }  // A-k1(t), B-k1(t) now resident
    BARRIER();

    // ================= P3: quad 0, k-half 1 =================
#pragma unroll
    for (int i = 0; i < 4; ++i)
      av[i] = *(const bf16x8*)(bufA + 16384 + (wr * 8 + i) * 1024 + laneoff);
#pragma unroll
    for (int j = 0; j < 4; ++j)
      bv[j] = *(const bf16x8*)(bufB + 16384 + (wc * 4 + j) * 1024 + laneoff);
    if (pf) STAGE_A(nb, t + 1, 1);
    BARRIER();
    LGKM0();
    __builtin_amdgcn_s_setprio(1);
#pragma unroll
    for (int i = 0; i < 4; ++i)
#pragma unroll
      for (int j = 0; j < 4; ++j)
        acc[i][j] = __builtin_amdgcn_mfma_f32_16x16x32_bf16(av[i], bv[j], acc[i][j], 0, 0, 0);
    __builtin_amdgcn_s_setprio(0);
    BARRIER();

    // ================= P4: quad 1, k-half 1 =================
#pragma unroll
    for (int i = 0; i < 4; ++i)
      av[i] = *(const bf16x8*)(bufA + 16384 + (wr * 8 + 4 + i) * 1024 + laneoff);
    if (pf) STAGE_B(nb, t + 1, 1);
    BARRIER();
    LGKM0();
    __builtin_amdgcn_s_setprio(1);
#pragma unroll
    for (int i = 0; i < 4; ++i)
#pragma unroll
      for (int j = 0; j < 4; ++j)
        acc[4 + i][j] = __builtin_amdgcn_mfma_f32_16x16x32_bf16(av[i], bv[j], acc[4 + i][j], 0, 0, 0);
    __builtin_amdgcn_s_setprio(0);
    LGKM0();   // reads of buf b complete before writers of buf b pass barrier
    VMCNT4();  // A-k0(t+1), B-k0(t+1) resident (oldest 4 of 8 outstanding)
    BARRIER();
  }
#undef STAGE_A
#undef STAGE_B

  // ---- epilogue: C/D mapping col = lane&15, row = (lane>>4)*4 + q
  const int er = (lane >> 4) * 4;
  const int ec = lane & 15;
#pragma unroll
  for (int i = 0; i < 8; ++i) {
    long rbase = m0 + wr * 128 + i * 16 + er;
#pragma unroll
    for (int j = 0; j < 4; ++j) {
      long cbase = n0 + wc * 64 + j * 16 + ec;
#pragma unroll
      for (int q = 0; q < 4; ++q)
        C[(rbase + q) * OUT_F + cbase] = acc[i][j][q];
    }
  }
}

// ---------------------------------------------------------------------------
// Fallback (ws too small): slow but correct fp32 path.
// ---------------------------------------------------------------------------
__global__ __launch_bounds__(256) void fallback_kernel(
    const float* __restrict__ x, const int* __restrict__ bw,
    const float* __restrict__ scales, const float* __restrict__ vals,
    const int* __restrict__ cols, const int* __restrict__ rptr,
    float* __restrict__ out) {
  const int oc  = blockIdx.x * 64 + (threadIdx.x & 63);
  const int tok = blockIdx.y * 4 + (threadIdx.x >> 6);
  const float s = scales[oc];
  const int* bwr = bw + (size_t)oc * (IN_F / 2);
  const float* xr = x + (size_t)tok * IN_F;
  float acc = 0.f;
  for (int j = 0; j < IN_F / 2; ++j) {
    int p = bwr[j];
    int lo = p & 15;        lo = (lo >= 8) ? lo - 16 : lo;
    int hi = (p >> 4) & 15; hi = (hi >= 8) ? hi - 16 : hi;
    acc += ((float)lo * s) * xr[2 * j] + ((float)hi * s) * xr[2 * j + 1];
  }
  const int b = rptr[oc], e = rptr[oc + 1];
  for (int t = b; t < e; ++t) acc += vals[t] * xr[cols[t]];
  out[(size_t)tok * OUT_F + oc] = acc;
}

extern "C" void kernel_launch(void* const* d_in, const int* in_sizes, int n_in,
                              void* d_out, int out_size, void* d_ws, size_t ws_size,
                              hipStream_t stream) {
  const float* x      = (const float*)d_in[0];
  const int*   bw     = (const int*)d_in[1];
  const float* scales = (const float*)d_in[2];
  const float* vals   = (const float*)d_in[3];
  const int*   cols   = (const int*)d_in[4];
  const int*   rptr   = (const int*)d_in[5];
  float* out = (float*)d_out;

  const size_t wbytes = (size_t)OUT_F * IN_F * 2;   // 32 MB bf16 W
  const size_t xbytes = (size_t)TOKENS * IN_F * 2;  // 64 MB bf16 X

  if (ws_size >= wbytes + xbytes) {
    unsigned short* W  = (unsigned short*)d_ws;
    unsigned short* Xb = (unsigned short*)((char*)d_ws + wbytes);
    prep_w<<<OUT_F, 256, 0, stream>>>(bw, scales, vals, cols, rptr, W);
    cvt_x<<<2048, 256, 0, stream>>>((const float4*)x, (ushort4*)Xb,
                                    TOKENS * IN_F / 4);
    gemm_bf16_8ph<<<(TOKENS / BM) * (OUT_F / BN), 512, 0, stream>>>(Xb, W, out);
  } else {
    dim3 grid(OUT_F / 64, TOKENS / 4);
    fallback_kernel<<<grid, 256, 0, stream>>>(x, bw, scales, vals, cols, rptr, out);
  }
}

// Round 6
// 292.851 us; speedup vs baseline: 1.0003x; 1.0003x over previous
//
#include <hip/hip_runtime.h>
#include <hip/hip_bf16.h>

#define TOKENS 8192
#define IN_F   4096
#define OUT_F  4096

// GEMM geometry: 256x256 tile, BK=64, 8 waves (2M x 4N), 512 threads
#define BM 256
#define BN 256
#define BK 64
#define NT (IN_F / BK)   // 64 K-tiles

typedef float  f32x4  __attribute__((ext_vector_type(4)));
typedef __bf16 bf16x8 __attribute__((ext_vector_type(8)));

#define BARRIER() asm volatile("s_barrier" ::: "memory")
#define VMCNT4()  asm volatile("s_waitcnt vmcnt(4)" ::: "memory")
#define VMCNT0()  asm volatile("s_waitcnt vmcnt(0)" ::: "memory")
#define LGKM0()   asm volatile("s_waitcnt lgkmcnt(0)" ::: "memory")

// fp32 -> bf16 round-to-nearest-even
__device__ __forceinline__ unsigned short f2bf(float f) {
  unsigned u = __builtin_bit_cast(unsigned, f);
  u += 0x7FFFu + ((u >> 16) & 1u);
  return (unsigned short)(u >> 16);
}

__device__ __forceinline__ void gload_lds16(const void* g, void* l) {
  __builtin_amdgcn_global_load_lds(
      (const __attribute__((address_space(1))) void*)g,
      (__attribute__((address_space(3))) void*)l, 16, 0, 0);
}

// ---------------------------------------------------------------------------
// Kernel 1: W = dequant_int4(base_weight)*scale + CSR ortho  ->  bf16 [OUT_F][IN_F]
// ---------------------------------------------------------------------------
__global__ __launch_bounds__(256) void prep_w(
    const int* __restrict__ bw, const float* __restrict__ scales,
    const float* __restrict__ vals, const int* __restrict__ cols,
    const int* __restrict__ rptr, unsigned short* __restrict__ W) {
  __shared__ float row[IN_F];
  const int n = blockIdx.x;
  const float s = scales[n];
  const int* bwr = bw + (size_t)n * (IN_F / 2);
#pragma unroll
  for (int it = 0; it < (IN_F / 2) / 256; ++it) {
    int j = it * 256 + threadIdx.x;
    int p = bwr[j];
    int lo = p & 15;        lo = (lo >= 8) ? lo - 16 : lo;
    int hi = (p >> 4) & 15; hi = (hi >= 8) ? hi - 16 : hi;
    row[2 * j]     = (float)lo * s;
    row[2 * j + 1] = (float)hi * s;
  }
  __syncthreads();
  const int b = rptr[n], e = rptr[n + 1];
  for (int t = b + (int)threadIdx.x; t < e; t += 256)
    atomicAdd(&row[cols[t]], vals[t]);
  __syncthreads();
  unsigned short* Wr = W + (size_t)n * IN_F;
#pragma unroll
  for (int it = 0; it < IN_F / 256; ++it) {
    int j = it * 256 + threadIdx.x;
    Wr[j] = f2bf(row[j]);
  }
}

// ---------------------------------------------------------------------------
// Kernel 2: X fp32 -> bf16
// ---------------------------------------------------------------------------
__global__ __launch_bounds__(256) void cvt_x(const float4* __restrict__ x,
                                             ushort4* __restrict__ xb, int nvec) {
  int i = blockIdx.x * blockDim.x + threadIdx.x;
  int stride = gridDim.x * blockDim.x;
  for (; i < nvec; i += stride) {
    float4 v = x[i];
    ushort4 o;
    o.x = f2bf(v.x); o.y = f2bf(v.y); o.z = f2bf(v.z); o.w = f2bf(v.w);
    xb[i] = o;
  }
}

// ---------------------------------------------------------------------------
// Kernel 3: 256x256 8-phase GEMM. C[M,N] = A[M,K] x B[N,K]^T, bf16 in, f32 out.
//
// LDS tile layout (per 256x64 operand tile, 32 KB):
//   byte(r,k) = (k>>5)*16384 + (r>>4)*1024 + (r&15)*64 + (k&31)*2
//   then byte ^= ((byte>>9)&1)<<5        (st_16x32 XOR swizzle)
// global_load_lds writes LINEAR dest (thread t -> bytes t*16); the global
// source address is the inverse-swizzled element, so LDS holds the swizzled
// layout and readers apply the same XOR. (both-sides rule, m104/m201)
//
// Schedule per K-tile (4 phases): (q0,k0)(q1,k0)(q0,k1)(q1,k1); each phase
// stages one 16KB unit of tile t+1 into the other buffer; vmcnt(4) only at
// even-phase boundaries (the 4 loads needed next are always the oldest 4
// of <=8 outstanding).
// ---------------------------------------------------------------------------
__global__ __launch_bounds__(512, 2) void gemm_bf16_8ph(
    const unsigned short* __restrict__ A,   // [TOKENS][IN_F] bf16
    const unsigned short* __restrict__ B,   // [OUT_F][IN_F] bf16
    float* __restrict__ C) {                // [TOKENS][OUT_F] f32
  __shared__ __align__(16) char lds[131072];  // 2 buf x (A 32K + B 32K)

  const int nbn = OUT_F / BN;               // 16
  const int cpx = ((TOKENS / BM) * nbn) >> 3;  // 512/8 = 64
  const int bid = blockIdx.x;
  const int swz = (bid & 7) * cpx + (bid >> 3);
  const int tm = swz / nbn, tn = swz % nbn;
  const long m0 = (long)tm * BM;
  const long n0 = (long)tn * BN;

  const int tid  = threadIdx.x;
  const int lane = tid & 63;
  const int wid  = tid >> 6;                // 0..7
  const int wr   = wid >> 2;                // 0..1
  const int wc   = wid & 3;                 // 0..3

  // ---- staging precompute: linear LDS byte p -> logical (r, k) (inverse swz)
  const int p0 = tid * 16;
  const int p1 = tid * 16 + 8192;
  const int lin0 = p0 ^ (((p0 >> 9) & 1) << 5);
  const int lin1 = p1 ^ (((p1 >> 9) & 1) << 5);
  const int r0 = (((p0 >> 10) & 15) << 4) | ((lin0 >> 6) & 15);
  const int r1 = (((p1 >> 10) & 15) << 4) | ((lin1 >> 6) & 15);
  const int k0 = (lin0 >> 1) & 31;
  const int k1 = (lin1 >> 1) & 31;

  const unsigned short* Abase = A + m0 * IN_F;
  const unsigned short* Bbase = B + n0 * IN_F;

  // ---- reader lane offset (with XOR swizzle; bit9 == bit3 of (lane&15))
  int laneoff = ((lane & 15) << 6) | ((lane >> 4) << 4);
  laneoff ^= ((laneoff >> 9) & 1) << 5;

#define STAGE_A(nb, kt, h)                                                    \
  do {                                                                        \
    gload_lds16(Abase + (size_t)r0 * IN_F + (kt) * 64 + (h) * 32 + k0,        \
                lds + (nb) * 65536 + (h) * 16384 + p0);                       \
    gload_lds16(Abase + (size_t)r1 * IN_F + (kt) * 64 + (h) * 32 + k1,        \
                lds + (nb) * 65536 + (h) * 16384 + p1);                       \
  } while (0)
#define STAGE_B(nb, kt, h)                                                    \
  do {                                                                        \
    gload_lds16(Bbase + (size_t)r0 * IN_F + (kt) * 64 + (h) * 32 + k0,        \
                lds + (nb) * 65536 + 32768 + (h) * 16384 + p0);               \
    gload_lds16(Bbase + (size_t)r1 * IN_F + (kt) * 64 + (h) * 32 + k1,        \
                lds + (nb) * 65536 + 32768 + (h) * 16384 + p1);               \
  } while (0)

  f32x4 acc[8][4];
#pragma unroll
  for (int i = 0; i < 8; ++i)
#pragma unroll
    for (int j = 0; j < 4; ++j) acc[i][j] = (f32x4)0.0f;

  // ---- prologue: stage tile 0 fully into buf 0
  STAGE_A(0, 0, 0);
  STAGE_B(0, 0, 0);
  STAGE_A(0, 0, 1);
  STAGE_B(0, 0, 1);
  VMCNT0();
  BARRIER();

  for (int t = 0; t < NT; ++t) {
    const int b  = t & 1;
    const int nb = b ^ 1;
    const char* bufA = lds + b * 65536;
    const char* bufB = lds + b * 65536 + 32768;
    const bool pf = (t + 1 < NT);
    bf16x8 av[4], bv[4];

    // ================= P1: quad 0, k-half 0 =================
#pragma unroll
    for (int i = 0; i < 4; ++i)
      av[i] = *(const bf16x8*)(bufA + (wr * 8 + i) * 1024 + laneoff);
#pragma unroll
    for (int j = 0; j < 4; ++j)
      bv[j] = *(const bf16x8*)(bufB + (wc * 4 + j) * 1024 + laneoff);
    if (pf) STAGE_A(nb, t + 1, 0);
    BARRIER();
    LGKM0();
    __builtin_amdgcn_s_setprio(1);
#pragma unroll
    for (int i = 0; i < 4; ++i)
#pragma unroll
      for (int j = 0; j < 4; ++j)
        acc[i][j] = __builtin_amdgcn_mfma_f32_16x16x32_bf16(av[i], bv[j], acc[i][j], 0, 0, 0);
    __builtin_amdgcn_s_setprio(0);
    BARRIER();

    // ================= P2: quad 1, k-half 0 =================
#pragma unroll
    for (int i = 0; i < 4; ++i)
      av[i] = *(const bf16x8*)(bufA + (wr * 8 + 4 + i) * 1024 + laneoff);
    if (pf) STAGE_B(nb, t + 1, 0);
    BARRIER();
    LGKM0();
    __builtin_amdgcn_s_setprio(1);
#pragma unroll
    for (int i = 0; i < 4; ++i)
#pragma unroll
      for (int j = 0; j < 4; ++j)
        acc[4 + i][j] = __builtin_amdgcn_mfma_f32_16x16x32_bf16(av[i], bv[j], acc[4 + i][j], 0, 0, 0);
    __builtin_amdgcn_s_setprio(0);
    if (pf) { VMCNT4(); } else { VMCNT0(); }  // A-k1(t), B-k1(t) now resident
    BARRIER();

    // ================= P3: quad 0, k-half 1 =================
#pragma unroll
    for (int i = 0; i < 4; ++i)
      av[i] = *(const bf16x8*)(bufA + 16384 + (wr * 8 + i) * 1024 + laneoff);
#pragma unroll
    for (int j = 0; j < 4; ++j)
      bv[j] = *(const bf16x8*)(bufB + 16384 + (wc * 4 + j) * 1024 + laneoff);
    if (pf) STAGE_A(nb, t + 1, 1);
    BARRIER();
    LGKM0();
    __builtin_amdgcn_s_setprio(1);
#pragma unroll
    for (int i = 0; i < 4; ++i)
#pragma unroll
      for (int j = 0; j < 4; ++j)
        acc[i][j] = __builtin_amdgcn_mfma_f32_16x16x32_bf16(av[i], bv[j], acc[i][j], 0, 0, 0);
    __builtin_amdgcn_s_setprio(0);
    BARRIER();

    // ================= P4: quad 1, k-half 1 =================
#pragma unroll
    for (int i = 0; i < 4; ++i)
      av[i] = *(const bf16x8*)(bufA + 16384 + (wr * 8 + 4 + i) * 1024 + laneoff);
    if (pf) STAGE_B(nb, t + 1, 1);
    BARRIER();
    LGKM0();
    __builtin_amdgcn_s_setprio(1);
#pragma unroll
    for (int i = 0; i < 4; ++i)
#pragma unroll
      for (int j = 0; j < 4; ++j)
        acc[4 + i][j] = __builtin_amdgcn_mfma_f32_16x16x32_bf16(av[i], bv[j], acc[4 + i][j], 0, 0, 0);
    __builtin_amdgcn_s_setprio(0);
    LGKM0();   // reads of buf b complete before writers of buf b pass barrier
    VMCNT4();  // A-k0(t+1), B-k0(t+1) resident (oldest 4 of 8 outstanding)
    BARRIER();
  }
#undef STAGE_A
#undef STAGE_B

  // ---- epilogue: C/D mapping col = lane&15, row = (lane>>4)*4 + q
  const int er = (lane >> 4) * 4;
  const int ec = lane & 15;
#pragma unroll
  for (int i = 0; i < 8; ++i) {
    long rbase = m0 + wr * 128 + i * 16 + er;
#pragma unroll
    for (int j = 0; j < 4; ++j) {
      long cbase = n0 + wc * 64 + j * 16 + ec;
#pragma unroll
      for (int q = 0; q < 4; ++q)
        C[(rbase + q) * OUT_F + cbase] = acc[i][j][q];
    }
  }
}

// ---------------------------------------------------------------------------
// Fallback (ws too small): slow but correct fp32 path.
// ---------------------------------------------------------------------------
__global__ __launch_bounds__(256) void fallback_kernel(
    const float* __restrict__ x, const int* __restrict__ bw,
    const float* __restrict__ scales, const float* __restrict__ vals,
    const int* __restrict__ cols, const int* __restrict__ rptr,
    float* __restrict__ out) {
  const int oc  = blockIdx.x * 64 + (threadIdx.x & 63);
  const int tok = blockIdx.y * 4 + (threadIdx.x >> 6);
  const float s = scales[oc];
  const int* bwr = bw + (size_t)oc * (IN_F / 2);
  const float* xr = x + (size_t)tok * IN_F;
  float acc = 0.f;
  for (int j = 0; j < IN_F / 2; ++j) {
    int p = bwr[j];
    int lo = p & 15;        lo = (lo >= 8) ? lo - 16 : lo;
    int hi = (p >> 4) & 15; hi = (hi >= 8) ? hi - 16 : hi;
    acc += ((float)lo * s) * xr[2 * j] + ((float)hi * s) * xr[2 * j + 1];
  }
  const int b = rptr[oc], e = rptr[oc + 1];
  for (int t = b; t < e; ++t) acc += vals[t] * xr[cols[t]];
  out[(size_t)tok * OUT_F + oc] = acc;
}

extern "C" void kernel_launch(void* const* d_in, const int* in_sizes, int n_in,
                              void* d_out, int out_size, void* d_ws, size_t ws_size,
                              hipStream_t stream) {
  const float* x      = (const float*)d_in[0];
  const int*   bw     = (const int*)d_in[1];
  const float* scales = (const float*)d_in[2];
  const float* vals   = (const float*)d_in[3];
  const int*   cols   = (const int*)d_in[4];
  const int*   rptr   = (const int*)d_in[5];
  float* out = (float*)d_out;

  const size_t wbytes = (size_t)OUT_F * IN_F * 2;   // 32 MB bf16 W
  const size_t xbytes = (size_t)TOKENS * IN_F * 2;  // 64 MB bf16 X

  if (ws_size >= wbytes + xbytes) {
    unsigned short* W  = (unsigned short*)d_ws;
    unsigned short* Xb = (unsigned short*)((char*)d_ws + wbytes);
    prep_w<<<OUT_F, 256, 0, stream>>>(bw, scales, vals, cols, rptr, W);
    cvt_x<<<2048, 256, 0, stream>>>((const float4*)x, (ushort4*)Xb,
                                    TOKENS * IN_F / 4);
    gemm_bf16_8ph<<<(TOKENS / BM) * (OUT_F / BN), 512, 0, stream>>>(Xb, W, out);
  } else {
    dim3 grid(OUT_F / 64, TOKENS / 4);
    fallback_kernel<<<grid, 256, 0, stream>>>(x, bw, scales, vals, cols, rptr, out);
  }
}

// Round 7
// 280.060 us; speedup vs baseline: 1.0460x; 1.0457x over previous
//
#include <hip/hip_runtime.h>
#include <hip/hip_bf16.h>

#define TOKENS 8192
#define IN_F   4096
#define OUT_F  4096

// GEMM geometry: 256x256 tile, BK=64, 8 waves (2M x 4N), 512 threads
#define BM 256
#define BN 256
#define BK 64
#define NT (IN_F / BK)   // 64 K-tiles

typedef float  f32x4  __attribute__((ext_vector_type(4)));
typedef __bf16 bf16x8 __attribute__((ext_vector_type(8)));

#define BARRIER() asm volatile("s_barrier" ::: "memory")
#define VMCNT4()  asm volatile("s_waitcnt vmcnt(4)" ::: "memory")
#define VMCNT2()  asm volatile("s_waitcnt vmcnt(2)" ::: "memory")
#define VMCNT0()  asm volatile("s_waitcnt vmcnt(0)" ::: "memory")

// fp32 -> bf16 round-to-nearest-even
__device__ __forceinline__ unsigned short f2bf(float f) {
  unsigned u = __builtin_bit_cast(unsigned, f);
  u += 0x7FFFu + ((u >> 16) & 1u);
  return (unsigned short)(u >> 16);
}

__device__ __forceinline__ void gload_lds16(const void* g, void* l) {
  __builtin_amdgcn_global_load_lds(
      (const __attribute__((address_space(1))) void*)g,
      (__attribute__((address_space(3))) void*)l, 16, 0, 0);
}

// ---------------------------------------------------------------------------
// Kernel 1: W = dequant_int4(base_weight)*scale + CSR ortho  ->  bf16 [OUT_F][IN_F]
// ---------------------------------------------------------------------------
__global__ __launch_bounds__(256) void prep_w(
    const int* __restrict__ bw, const float* __restrict__ scales,
    const float* __restrict__ vals, const int* __restrict__ cols,
    const int* __restrict__ rptr, unsigned short* __restrict__ W) {
  __shared__ float row[IN_F];
  const int n = blockIdx.x;
  const float s = scales[n];
  const int* bwr = bw + (size_t)n * (IN_F / 2);
#pragma unroll
  for (int it = 0; it < (IN_F / 2) / 256; ++it) {
    int j = it * 256 + threadIdx.x;
    int p = bwr[j];
    int lo = p & 15;        lo = (lo >= 8) ? lo - 16 : lo;
    int hi = (p >> 4) & 15; hi = (hi >= 8) ? hi - 16 : hi;
    row[2 * j]     = (float)lo * s;
    row[2 * j + 1] = (float)hi * s;
  }
  __syncthreads();
  const int b = rptr[n], e = rptr[n + 1];
  for (int t = b + (int)threadIdx.x; t < e; t += 256)
    atomicAdd(&row[cols[t]], vals[t]);
  __syncthreads();
  unsigned short* Wr = W + (size_t)n * IN_F;
#pragma unroll
  for (int it = 0; it < IN_F / 256; ++it) {
    int j = it * 256 + threadIdx.x;
    Wr[j] = f2bf(row[j]);
  }
}

// ---------------------------------------------------------------------------
// Kernel 2: X fp32 -> bf16
// ---------------------------------------------------------------------------
__global__ __launch_bounds__(256) void cvt_x(const float4* __restrict__ x,
                                             ushort4* __restrict__ xb, int nvec) {
  int i = blockIdx.x * blockDim.x + threadIdx.x;
  int stride = gridDim.x * blockDim.x;
  for (; i < nvec; i += stride) {
    float4 v = x[i];
    ushort4 o;
    o.x = f2bf(v.x); o.y = f2bf(v.y); o.z = f2bf(v.z); o.w = f2bf(v.w);
    xb[i] = o;
  }
}

// ---------------------------------------------------------------------------
// Kernel 3: 256x256 GEMM, one barrier per phase, register-subtile pipelined.
//
// LDS layout per 256x64 operand tile (32 KB):
//   byte(r,k) = (k>>5)*16384 + (r>>4)*1024 + (r&15)*64 + (k&31)*2, then
//   byte ^= ((byte>>9)&1)<<5   (st_16x32 XOR swizzle; staging pre-swizzles
//   the GLOBAL source address, LDS dest stays linear — both-sides rule)
//
// Phase p's MFMA consumes fragments loaded during phase p-1, so ds_reads
// overlap the MFMA cluster instead of sitting between barriers. Staging of
// tile t+1 (4 half-tiles, 2 loads each) is spread one unit per phase.
// vmcnt(2) before P2/P4 entry barriers retires exactly the oldest 2
// half-tiles = the data needed in the next two phases (6 loads outstanding
// at each wait point; degenerates to vmcnt(0) on the last tile).
// ---------------------------------------------------------------------------
__global__ __launch_bounds__(512, 2) void gemm_bf16_8ph(
    const unsigned short* __restrict__ A,   // [TOKENS][IN_F] bf16
    const unsigned short* __restrict__ B,   // [OUT_F][IN_F] bf16
    float* __restrict__ C) {                // [TOKENS][OUT_F] f32
  __shared__ __align__(16) char lds[131072];  // 2 buf x (A 32K + B 32K)

  const int nbn = OUT_F / BN;               // 16
  const int cpx = ((TOKENS / BM) * nbn) >> 3;  // 512/8 = 64
  const int bid = blockIdx.x;
  const int swz = (bid & 7) * cpx + (bid >> 3);
  const int tm = swz / nbn, tn = swz % nbn;
  const long m0 = (long)tm * BM;
  const long n0 = (long)tn * BN;

  const int tid  = threadIdx.x;
  const int lane = tid & 63;
  const int wid  = tid >> 6;                // 0..7
  const int wr   = wid >> 2;                // 0..1
  const int wc   = wid & 3;                 // 0..3

  // ---- staging precompute: linear LDS byte p -> logical (r, k) (inverse swz)
  const int p0 = tid * 16;
  const int p1 = tid * 16 + 8192;
  const int lin0 = p0 ^ (((p0 >> 9) & 1) << 5);
  const int lin1 = p1 ^ (((p1 >> 9) & 1) << 5);
  const int r0 = (((p0 >> 10) & 15) << 4) | ((lin0 >> 6) & 15);
  const int r1 = (((p1 >> 10) & 15) << 4) | ((lin1 >> 6) & 15);
  const int k0 = (lin0 >> 1) & 31;
  const int k1 = (lin1 >> 1) & 31;

  const unsigned short* Abase = A + m0 * IN_F;
  const unsigned short* Bbase = B + n0 * IN_F;

  // ---- reader lane offset (with XOR swizzle)
  int laneoff = ((lane & 15) << 6) | ((lane >> 4) << 4);
  laneoff ^= ((laneoff >> 9) & 1) << 5;

#define STAGE_A(nb, kt, h)                                                    \
  do {                                                                        \
    gload_lds16(Abase + (size_t)r0 * IN_F + (kt) * 64 + (h) * 32 + k0,        \
                lds + (nb) * 65536 + (h) * 16384 + p0);                       \
    gload_lds16(Abase + (size_t)r1 * IN_F + (kt) * 64 + (h) * 32 + k1,        \
                lds + (nb) * 65536 + (h) * 16384 + p1);                       \
  } while (0)
#define STAGE_B(nb, kt, h)                                                    \
  do {                                                                        \
    gload_lds16(Bbase + (size_t)r0 * IN_F + (kt) * 64 + (h) * 32 + k0,        \
                lds + (nb) * 65536 + 32768 + (h) * 16384 + p0);               \
    gload_lds16(Bbase + (size_t)r1 * IN_F + (kt) * 64 + (h) * 32 + k1,        \
                lds + (nb) * 65536 + 32768 + (h) * 16384 + p1);               \
  } while (0)

  f32x4 acc[8][4];
#pragma unroll
  for (int i = 0; i < 8; ++i)
#pragma unroll
    for (int j = 0; j < 4; ++j) acc[i][j] = (f32x4)0.0f;

  // fragment register sets (named, statically indexed — rule #20)
  bf16x8 av1[4], av2[4], av3[4], av4[4], bv1[4], bv3[4];

  // ---- prologue: stage tile 0 fully into buf 0; preload s1(t0)
  STAGE_A(0, 0, 0);
  STAGE_B(0, 0, 0);
  STAGE_A(0, 0, 1);
  STAGE_B(0, 0, 1);
  VMCNT4();           // A-h0, B-h0 of tile 0 resident (per-wave)
  BARRIER();          // ... for ALL waves
#pragma unroll
  for (int i = 0; i < 4; ++i)
    av1[i] = *(const bf16x8*)(lds + (wr * 8 + i) * 1024 + laneoff);
#pragma unroll
  for (int j = 0; j < 4; ++j)
    bv1[j] = *(const bf16x8*)(lds + 32768 + (wc * 4 + j) * 1024 + laneoff);

  for (int t = 0; t < NT; ++t) {
    const int b  = t & 1;
    const int nb = b ^ 1;
    const char* bufA  = lds + b * 65536;
    const char* bufB  = bufA + 32768;
    const char* nbufA = lds + nb * 65536;
    const char* nbufB = nbufA + 32768;
    const bool pf = (t + 1 < NT);

    // ===== P1: MFMA s1 (av1,bv1)  |  load s2 (av2)  |  stage A-h0(t+1)
    BARRIER();
    __builtin_amdgcn_s_setprio(1);
    if (pf) STAGE_A(nb, t + 1, 0);
#pragma unroll
    for (int i = 0; i < 4; ++i)
      av2[i] = *(const bf16x8*)(bufA + (wr * 8 + 4 + i) * 1024 + laneoff);
#pragma unroll
    for (int i = 0; i < 4; ++i)
#pragma unroll
      for (int j = 0; j < 4; ++j)
        acc[i][j] = __builtin_amdgcn_mfma_f32_16x16x32_bf16(av1[i], bv1[j], acc[i][j], 0, 0, 0);
    __builtin_amdgcn_s_setprio(0);

    // ===== P2: MFMA s2 (av2,bv1)  |  load s3 (av3,bv3)  |  stage B-h0(t+1)
    if (pf) { VMCNT2(); } else { VMCNT0(); }  // A-h1(t), B-h1(t) resident
    BARRIER();
    __builtin_amdgcn_s_setprio(1);
    if (pf) STAGE_B(nb, t + 1, 0);
#pragma unroll
    for (int i = 0; i < 4; ++i)
      av3[i] = *(const bf16x8*)(bufA + 16384 + (wr * 8 + i) * 1024 + laneoff);
#pragma unroll
    for (int j = 0; j < 4; ++j)
      bv3[j] = *(const bf16x8*)(bufB + 16384 + (wc * 4 + j) * 1024 + laneoff);
#pragma unroll
    for (int i = 0; i < 4; ++i)
#pragma unroll
      for (int j = 0; j < 4; ++j)
        acc[4 + i][j] = __builtin_amdgcn_mfma_f32_16x16x32_bf16(av2[i], bv1[j], acc[4 + i][j], 0, 0, 0);
    __builtin_amdgcn_s_setprio(0);

    // ===== P3: MFMA s3 (av3,bv3)  |  load s4 (av4)  |  stage A-h1(t+1)
    BARRIER();
    __builtin_amdgcn_s_setprio(1);
    if (pf) STAGE_A(nb, t + 1, 1);
#pragma unroll
    for (int i = 0; i < 4; ++i)
      av4[i] = *(const bf16x8*)(bufA + 16384 + (wr * 8 + 4 + i) * 1024 + laneoff);
#pragma unroll
    for (int i = 0; i < 4; ++i)
#pragma unroll
      for (int j = 0; j < 4; ++j)
        acc[i][j] = __builtin_amdgcn_mfma_f32_16x16x32_bf16(av3[i], bv3[j], acc[i][j], 0, 0, 0);
    __builtin_amdgcn_s_setprio(0);

    // ===== P4: MFMA s4 (av4,bv3)  |  load s1(t+1) from buf nb  |  stage B-h1(t+1)
    if (pf) { VMCNT2(); } else { VMCNT0(); }  // A-h0(t+1), B-h0(t+1) resident
    BARRIER();
    __builtin_amdgcn_s_setprio(1);
    if (pf) {
      STAGE_B(nb, t + 1, 1);
#pragma unroll
      for (int i = 0; i < 4; ++i)
        av1[i] = *(const bf16x8*)(nbufA + (wr * 8 + i) * 1024 + laneoff);
#pragma unroll
      for (int j = 0; j < 4; ++j)
        bv1[j] = *(const bf16x8*)(nbufB + (wc * 4 + j) * 1024 + laneoff);
    }
#pragma unroll
    for (int i = 0; i < 4; ++i)
#pragma unroll
      for (int j = 0; j < 4; ++j)
        acc[4 + i][j] = __builtin_amdgcn_mfma_f32_16x16x32_bf16(av4[i], bv3[j], acc[4 + i][j], 0, 0, 0);
    __builtin_amdgcn_s_setprio(0);
  }
#undef STAGE_A
#undef STAGE_B

  // ---- epilogue: C/D mapping col = lane&15, row = (lane>>4)*4 + q
  const int er = (lane >> 4) * 4;
  const int ec = lane & 15;
#pragma unroll
  for (int i = 0; i < 8; ++i) {
    long rbase = m0 + wr * 128 + i * 16 + er;
#pragma unroll
    for (int j = 0; j < 4; ++j) {
      long cbase = n0 + wc * 64 + j * 16 + ec;
#pragma unroll
      for (int q = 0; q < 4; ++q)
        C[(rbase + q) * OUT_F + cbase] = acc[i][j][q];
    }
  }
}

// ---------------------------------------------------------------------------
// Fallback (ws too small): slow but correct fp32 path.
// ---------------------------------------------------------------------------
__global__ __launch_bounds__(256) void fallback_kernel(
    const float* __restrict__ x, const int* __restrict__ bw,
    const float* __restrict__ scales, const float* __restrict__ vals,
    const int* __restrict__ cols, const int* __restrict__ rptr,
    float* __restrict__ out) {
  const int oc  = blockIdx.x * 64 + (threadIdx.x & 63);
  const int tok = blockIdx.y * 4 + (threadIdx.x >> 6);
  const float s = scales[oc];
  const int* bwr = bw + (size_t)oc * (IN_F / 2);
  const float* xr = x + (size_t)tok * IN_F;
  float acc = 0.f;
  for (int j = 0; j < IN_F / 2; ++j) {
    int p = bwr[j];
    int lo = p & 15;        lo = (lo >= 8) ? lo - 16 : lo;
    int hi = (p >> 4) & 15; hi = (hi >= 8) ? hi - 16 : hi;
    acc += ((float)lo * s) * xr[2 * j] + ((float)hi * s) * xr[2 * j + 1];
  }
  const int b = rptr[oc], e = rptr[oc + 1];
  for (int t = b; t < e; ++t) acc += vals[t] * xr[cols[t]];
  out[(size_t)tok * OUT_F + oc] = acc;
}

extern "C" void kernel_launch(void* const* d_in, const int* in_sizes, int n_in,
                              void* d_out, int out_size, void* d_ws, size_t ws_size,
                              hipStream_t stream) {
  const float* x      = (const float*)d_in[0];
  const int*   bw     = (const int*)d_in[1];
  const float* scales = (const float*)d_in[2];
  const float* vals   = (const float*)d_in[3];
  const int*   cols   = (const int*)d_in[4];
  const int*   rptr   = (const int*)d_in[5];
  float* out = (float*)d_out;

  const size_t wbytes = (size_t)OUT_F * IN_F * 2;   // 32 MB bf16 W
  const size_t xbytes = (size_t)TOKENS * IN_F * 2;  // 64 MB bf16 X

  if (ws_size >= wbytes + xbytes) {
    unsigned short* W  = (unsigned short*)d_ws;
    unsigned short* Xb = (unsigned short*)((char*)d_ws + wbytes);
    prep_w<<<OUT_F, 256, 0, stream>>>(bw, scales, vals, cols, rptr, W);
    cvt_x<<<2048, 256, 0, stream>>>((const float4*)x, (ushort4*)Xb,
                                    TOKENS * IN_F / 4);
    gemm_bf16_8ph<<<(TOKENS / BM) * (OUT_F / BN), 512, 0, stream>>>(Xb, W, out);
  } else {
    dim3 grid(OUT_F / 64, TOKENS / 4);
    fallback_kernel<<<grid, 256, 0, stream>>>(x, bw, scales, vals, cols, rptr, out);
  }
}

// Round 8
// 232.117 us; speedup vs baseline: 1.2620x; 1.2065x over previous
//
#include <hip/hip_runtime.h>
#include <hip/hip_bf16.h>

#define TOKENS 8192
#define IN_F   4096
#define OUT_F  4096

// GEMM geometry: 256x256 tile, K_STEP=128 (2 x K=64 MFMA steps), 8 waves
#define BM 256
#define BN 256
#define KSTEP 128
#define NT (IN_F / KSTEP)   // 32 K-tiles

typedef int   i32x4  __attribute__((ext_vector_type(4)));

#define BARRIER() asm volatile("s_barrier" ::: "memory")
#define VMCNT4()  asm volatile("s_waitcnt vmcnt(4)" ::: "memory")
#define VMCNT2()  asm volatile("s_waitcnt vmcnt(2)" ::: "memory")
#define VMCNT0()  asm volatile("s_waitcnt vmcnt(0)" ::: "memory")

__device__ __forceinline__ void gload_lds16(const void* g, void* l) {
  __builtin_amdgcn_global_load_lds(
      (const __attribute__((address_space(1))) void*)g,
      (__attribute__((address_space(3))) void*)l, 16, 0, 0);
}

__device__ __forceinline__ float blockmax256(float m, float* red) {
  // 256 threads: wave shfl reduce then 4-entry LDS combine
#pragma unroll
  for (int off = 32; off; off >>= 1)
    m = fmaxf(m, __shfl_xor(m, off, 64));
  if ((threadIdx.x & 63) == 0) red[threadIdx.x >> 6] = m;
  __syncthreads();
  return fmaxf(fmaxf(red[0], red[1]), fmaxf(red[2], red[3]));
}

__device__ __forceinline__ int pack4(const float* v, float inv) {
  unsigned w = 0;
#pragma unroll
  for (int b = 0; b < 4; ++b) {
    int q = __float2int_rn(fmaxf(fminf(v[b] * inv, 127.f), -127.f));
    w |= ((unsigned)(unsigned char)(signed char)q) << (8 * b);
  }
  return (int)w;
}

// ---------------------------------------------------------------------------
// Kernel 1: W_full = dequant_int4 + CSR ortho -> per-row i8 quant + scale.
// One block per output row; fp32 row staged in LDS (handles duplicate cols).
// ---------------------------------------------------------------------------
__global__ __launch_bounds__(256) void prep_w_i8(
    const int* __restrict__ bw, const float* __restrict__ scales,
    const float* __restrict__ vals, const int* __restrict__ cols,
    const int* __restrict__ rptr, signed char* __restrict__ Wq,
    float* __restrict__ sw) {
  __shared__ float row[IN_F];
  __shared__ float red[4];
  const int n = blockIdx.x;
  const int tid = threadIdx.x;
  const float s = scales[n];
  const int* bwr = bw + (size_t)n * (IN_F / 2);
#pragma unroll
  for (int it = 0; it < (IN_F / 2) / 256; ++it) {
    int j = it * 256 + tid;
    int p = bwr[j];
    int lo = p & 15;        lo = (lo >= 8) ? lo - 16 : lo;
    int hi = (p >> 4) & 15; hi = (hi >= 8) ? hi - 16 : hi;
    row[2 * j]     = (float)lo * s;
    row[2 * j + 1] = (float)hi * s;
  }
  __syncthreads();
  const int b = rptr[n], e = rptr[n + 1];
  for (int t = b + tid; t < e; t += 256)
    atomicAdd(&row[cols[t]], vals[t]);
  __syncthreads();
  float m = 0.f;
#pragma unroll
  for (int it = 0; it < IN_F / 256; ++it)
    m = fmaxf(m, fabsf(row[it * 256 + tid]));
  const float mm  = fmaxf(blockmax256(m, red), 1e-30f);
  const float inv = 127.f / mm;
  // pack 16 i8 per thread, 16B store
  int4 w;
  w.x = pack4(&row[tid * 16 + 0],  inv);
  w.y = pack4(&row[tid * 16 + 4],  inv);
  w.z = pack4(&row[tid * 16 + 8],  inv);
  w.w = pack4(&row[tid * 16 + 12], inv);
  *(int4*)(Wq + (size_t)n * IN_F + tid * 16) = w;
  if (tid == 0) sw[n] = mm / 127.f;
}

// ---------------------------------------------------------------------------
// Kernel 2: X fp32 -> per-token i8 quant + scale. One block per token.
// ---------------------------------------------------------------------------
__global__ __launch_bounds__(256) void cvt_x_i8(
    const float4* __restrict__ x, int* __restrict__ xq,
    float* __restrict__ sx) {
  __shared__ float red[4];
  const int tok = blockIdx.x;
  const int tid = threadIdx.x;
  const float4* xr = x + (size_t)tok * (IN_F / 4);
  float4 v[4];
  float m = 0.f;
#pragma unroll
  for (int j = 0; j < 4; ++j) {
    v[j] = xr[j * 256 + tid];
    m = fmaxf(m, fmaxf(fmaxf(fabsf(v[j].x), fabsf(v[j].y)),
                       fmaxf(fabsf(v[j].z), fabsf(v[j].w))));
  }
  const float mm  = fmaxf(blockmax256(m, red), 1e-30f);
  const float inv = 127.f / mm;
  int* xo = xq + (size_t)tok * (IN_F / 4);
#pragma unroll
  for (int j = 0; j < 4; ++j) {
    float vv[4] = {v[j].x, v[j].y, v[j].z, v[j].w};
    xo[j * 256 + tid] = pack4(vv, inv);
  }
  if (tid == 0) sx[tok] = mm / 127.f;
}

// ---------------------------------------------------------------------------
// Kernel 3: i8 GEMM, R7 sync skeleton, K_STEP=128 (2 x mfma_i32_16x16x64_i8).
//
// LDS per 256x128 operand tile = 32KB, as two 16KB k-halves h in {0,1}.
// Within a half: byte(r, k64) = (k64>>4)*4096 + r*16 + (k64&15).
// Quarter-wave frag reads are 16 consecutive rows x 16B = 256 contiguous
// bytes -> 2-way bank aliasing (free, m136). Staging is linear-dest
// global_load_lds; per-thread source = row (tid&255), k16-block from tid>>8.
//
// Phases P1..P4 per K-tile, one barrier each; phase p's MFMA consumes
// fragments ds_read in phase p-1; staging spread 2 gloads/phase;
// vmcnt(2) at P2/P4 entries retires exactly the oldest 4 of 6 outstanding
// (identical schedule semantics to the verified R7 bf16 kernel).
// ---------------------------------------------------------------------------
__global__ __launch_bounds__(512, 2) void gemm_i8(
    const unsigned char* __restrict__ A,   // [TOKENS][IN_F] i8
    const unsigned char* __restrict__ B,   // [OUT_F][IN_F] i8
    const float* __restrict__ sx,          // [TOKENS]
    const float* __restrict__ sw,          // [OUT_F]
    float* __restrict__ C) {               // [TOKENS][OUT_F] f32
  __shared__ __align__(16) char lds[131072];  // 2 buf x (A 32K + B 32K)

  const int nbn = OUT_F / BN;                  // 16
  const int cpx = ((TOKENS / BM) * nbn) >> 3;  // 512/8 = 64
  const int bid = blockIdx.x;
  const int swz = (bid & 7) * cpx + (bid >> 3);
  const int tm = swz / nbn, tn = swz % nbn;
  const long m0 = (long)tm * BM;
  const long n0 = (long)tn * BN;

  const int tid  = threadIdx.x;
  const int lane = tid & 63;
  const int wid  = tid >> 6;                // 0..7
  const int wr   = wid >> 2;                // 0..1
  const int wc   = wid & 3;                 // 0..3

  // staging: thread covers row rr, 16B k-block h4 of each 16KB half
  const int p0  = tid * 16;
  const int p1  = p0 + 8192;
  const int rr  = tid & 255;
  const int h4a = tid >> 8;                 // 0..1
  const int h4b = 2 + (tid >> 8);           // 2..3

  const unsigned char* Abase = A + m0 * IN_F;
  const unsigned char* Bbase = B + n0 * IN_F;

  // reader: quarter-wave q=lane>>4 owns k16-block q; row = (lane&15) + base
  const int laneoff = (lane >> 4) * 4096 + (lane & 15) * 16;

#define STAGE_A(nb, kt, h)                                                      \
  do {                                                                          \
    gload_lds16(Abase + (size_t)rr * IN_F + (kt) * 128 + (h) * 64 + h4a * 16,   \
                lds + (nb) * 65536 + (h) * 16384 + p0);                         \
    gload_lds16(Abase + (size_t)rr * IN_F + (kt) * 128 + (h) * 64 + h4b * 16,   \
                lds + (nb) * 65536 + (h) * 16384 + p1);                         \
  } while (0)
#define STAGE_B(nb, kt, h)                                                      \
  do {                                                                          \
    gload_lds16(Bbase + (size_t)rr * IN_F + (kt) * 128 + (h) * 64 + h4a * 16,   \
                lds + (nb) * 65536 + 32768 + (h) * 16384 + p0);                 \
    gload_lds16(Bbase + (size_t)rr * IN_F + (kt) * 128 + (h) * 64 + h4b * 16,   \
                lds + (nb) * 65536 + 32768 + (h) * 16384 + p1);                 \
  } while (0)

  i32x4 acc[8][4];
#pragma unroll
  for (int i = 0; i < 8; ++i)
#pragma unroll
    for (int j = 0; j < 4; ++j) acc[i][j] = (i32x4)0;

  // fragment register sets (named, statically indexed — rule #20)
  i32x4 av1[4], av2[4], av3[4], av4[4], bv1[4], bv3[4];

  // ---- prologue: stage tile 0 into buf 0; preload s1(t0) after h0 resident
  STAGE_A(0, 0, 0);
  STAGE_B(0, 0, 0);
  STAGE_A(0, 0, 1);
  STAGE_B(0, 0, 1);
  VMCNT4();           // h0 of tile 0 resident (per-wave)
  BARRIER();
#pragma unroll
  for (int i = 0; i < 4; ++i)
    av1[i] = *(const i32x4*)(lds + wr * 2048 + i * 256 + laneoff);
#pragma unroll
  for (int j = 0; j < 4; ++j)
    bv1[j] = *(const i32x4*)(lds + 32768 + wc * 1024 + j * 256 + laneoff);

  for (int t = 0; t < NT; ++t) {
    const int b  = t & 1;
    const int nb = b ^ 1;
    const char* bufA  = lds + b * 65536;
    const char* bufB  = bufA + 32768;
    const char* nbufA = lds + nb * 65536;
    const char* nbufB = nbufA + 32768;
    const bool pf = (t + 1 < NT);

    // ===== P1: MFMA s1 (av1,bv1: rows lo, h0) | load av2 | stage A-h0(t+1)
    BARRIER();
    __builtin_amdgcn_s_setprio(1);
    if (pf) STAGE_A(nb, t + 1, 0);
#pragma unroll
    for (int i = 0; i < 4; ++i)
      av2[i] = *(const i32x4*)(bufA + wr * 2048 + (4 + i) * 256 + laneoff);
#pragma unroll
    for (int i = 0; i < 4; ++i)
#pragma unroll
      for (int j = 0; j < 4; ++j)
        acc[i][j] = __builtin_amdgcn_mfma_i32_16x16x64_i8(av1[i], bv1[j], acc[i][j], 0, 0, 0);
    __builtin_amdgcn_s_setprio(0);

    // ===== P2: MFMA s2 (av2,bv1) | load av3,bv3 (h1) | stage B-h0(t+1)
    if (pf) { VMCNT2(); } else { VMCNT0(); }  // A-h1(t), B-h1(t) resident
    BARRIER();
    __builtin_amdgcn_s_setprio(1);
    if (pf) STAGE_B(nb, t + 1, 0);
#pragma unroll
    for (int i = 0; i < 4; ++i)
      av3[i] = *(const i32x4*)(bufA + 16384 + wr * 2048 + i * 256 + laneoff);
#pragma unroll
    for (int j = 0; j < 4; ++j)
      bv3[j] = *(const i32x4*)(bufB + 16384 + wc * 1024 + j * 256 + laneoff);
#pragma unroll
    for (int i = 0; i < 4; ++i)
#pragma unroll
      for (int j = 0; j < 4; ++j)
        acc[4 + i][j] = __builtin_amdgcn_mfma_i32_16x16x64_i8(av2[i], bv1[j], acc[4 + i][j], 0, 0, 0);
    __builtin_amdgcn_s_setprio(0);

    // ===== P3: MFMA s3 (av3,bv3: rows lo, h1) | load av4 | stage A-h1(t+1)
    BARRIER();
    __builtin_amdgcn_s_setprio(1);
    if (pf) STAGE_A(nb, t + 1, 1);
#pragma unroll
    for (int i = 0; i < 4; ++i)
      av4[i] = *(const i32x4*)(bufA + 16384 + wr * 2048 + (4 + i) * 256 + laneoff);
#pragma unroll
    for (int i = 0; i < 4; ++i)
#pragma unroll
      for (int j = 0; j < 4; ++j)
        acc[i][j] = __builtin_amdgcn_mfma_i32_16x16x64_i8(av3[i], bv3[j], acc[i][j], 0, 0, 0);
    __builtin_amdgcn_s_setprio(0);

    // ===== P4: MFMA s4 (av4,bv3) | load s1(t+1) from buf nb | stage B-h1(t+1)
    if (pf) { VMCNT2(); } else { VMCNT0(); }  // A-h0(t+1), B-h0(t+1) resident
    BARRIER();
    __builtin_amdgcn_s_setprio(1);
    if (pf) {
      STAGE_B(nb, t + 1, 1);
#pragma unroll
      for (int i = 0; i < 4; ++i)
        av1[i] = *(const i32x4*)(nbufA + wr * 2048 + i * 256 + laneoff);
#pragma unroll
      for (int j = 0; j < 4; ++j)
        bv1[j] = *(const i32x4*)(nbufB + wc * 1024 + j * 256 + laneoff);
    }
#pragma unroll
    for (int i = 0; i < 4; ++i)
#pragma unroll
      for (int j = 0; j < 4; ++j)
        acc[4 + i][j] = __builtin_amdgcn_mfma_i32_16x16x64_i8(av4[i], bv3[j], acc[4 + i][j], 0, 0, 0);
    __builtin_amdgcn_s_setprio(0);
  }
#undef STAGE_A
#undef STAGE_B

  // ---- epilogue: C = i32acc * sx[row] * sw[col]; C/D map col=lane&15,
  // row=(lane>>4)*4+q (dtype-independent, m127/m128)
  const int er = (lane >> 4) * 4;
  const int ec = lane & 15;
#pragma unroll
  for (int i = 0; i < 8; ++i) {
    long rbase = m0 + wr * 128 + i * 16 + er;
    float sxq[4];
#pragma unroll
    for (int q = 0; q < 4; ++q) sxq[q] = sx[rbase + q];
#pragma unroll
    for (int j = 0; j < 4; ++j) {
      long cbase = n0 + wc * 64 + j * 16 + ec;
      const float swc = sw[cbase];
#pragma unroll
      for (int q = 0; q < 4; ++q)
        C[(rbase + q) * OUT_F + cbase] = (float)acc[i][j][q] * sxq[q] * swc;
    }
  }
}

// ---------------------------------------------------------------------------
// Fallback (ws too small): slow but correct fp32 path.
// ---------------------------------------------------------------------------
__global__ __launch_bounds__(256) void fallback_kernel(
    const float* __restrict__ x, const int* __restrict__ bw,
    const float* __restrict__ scales, const float* __restrict__ vals,
    const int* __restrict__ cols, const int* __restrict__ rptr,
    float* __restrict__ out) {
  const int oc  = blockIdx.x * 64 + (threadIdx.x & 63);
  const int tok = blockIdx.y * 4 + (threadIdx.x >> 6);
  const float s = scales[oc];
  const int* bwr = bw + (size_t)oc * (IN_F / 2);
  const float* xr = x + (size_t)tok * IN_F;
  float acc = 0.f;
  for (int j = 0; j < IN_F / 2; ++j) {
    int p = bwr[j];
    int lo = p & 15;        lo = (lo >= 8) ? lo - 16 : lo;
    int hi = (p >> 4) & 15; hi = (hi >= 8) ? hi - 16 : hi;
    acc += ((float)lo * s) * xr[2 * j] + ((float)hi * s) * xr[2 * j + 1];
  }
  const int b = rptr[oc], e = rptr[oc + 1];
  for (int t = b; t < e; ++t) acc += vals[t] * xr[cols[t]];
  out[(size_t)tok * OUT_F + oc] = acc;
}

extern "C" void kernel_launch(void* const* d_in, const int* in_sizes, int n_in,
                              void* d_out, int out_size, void* d_ws, size_t ws_size,
                              hipStream_t stream) {
  const float* x      = (const float*)d_in[0];
  const int*   bw     = (const int*)d_in[1];
  const float* scales = (const float*)d_in[2];
  const float* vals   = (const float*)d_in[3];
  const int*   cols   = (const int*)d_in[4];
  const int*   rptr   = (const int*)d_in[5];
  float* out = (float*)d_out;

  // workspace: Wq 16MB | Xq 32MB | sw 16KB | sx 32KB
  const size_t wq_off = 0;
  const size_t xq_off = (size_t)OUT_F * IN_F;            // 16 MB
  const size_t sw_off = xq_off + (size_t)TOKENS * IN_F;  // 48 MB
  const size_t sx_off = sw_off + 65536;
  const size_t need   = sx_off + 65536;

  if (ws_size >= need) {
    signed char* Wq = (signed char*)d_ws + wq_off;
    signed char* Xq = (signed char*)d_ws + xq_off;
    float* sw = (float*)((char*)d_ws + sw_off);
    float* sx = (float*)((char*)d_ws + sx_off);
    prep_w_i8<<<OUT_F, 256, 0, stream>>>(bw, scales, vals, cols, rptr, Wq, sw);
    cvt_x_i8<<<TOKENS, 256, 0, stream>>>((const float4*)x, (int*)Xq, sx);
    gemm_i8<<<(TOKENS / BM) * (OUT_F / BN), 512, 0, stream>>>(
        (const unsigned char*)Xq, (const unsigned char*)Wq, sx, sw, out);
  } else {
    dim3 grid(OUT_F / 64, TOKENS / 4);
    fallback_kernel<<<grid, 256, 0, stream>>>(x, bw, scales, vals, cols, rptr, out);
  }
}

// Round 9
// 183.479 us; speedup vs baseline: 1.5966x; 1.2651x over previous
//
#include <hip/hip_runtime.h>
#include <hip/hip_bf16.h>

#define TOKENS 8192
#define IN_F   4096
#define OUT_F  4096

// GEMM geometry: 256x256 tile, K_STEP=128 (2 x K=64 MFMA steps), 8 waves
#define BM 256
#define BN 256
#define KSTEP 128
#define NT (IN_F / KSTEP)   // 32 K-tiles

typedef int   i32x4  __attribute__((ext_vector_type(4)));

#define BARRIER() asm volatile("s_barrier" ::: "memory")
#define VMCNT4()  asm volatile("s_waitcnt vmcnt(4)" ::: "memory")
#define VMCNT2()  asm volatile("s_waitcnt vmcnt(2)" ::: "memory")
#define VMCNT0()  asm volatile("s_waitcnt vmcnt(0)" ::: "memory")

__device__ __forceinline__ void gload_lds16(const void* g, void* l) {
  __builtin_amdgcn_global_load_lds(
      (const __attribute__((address_space(1))) void*)g,
      (__attribute__((address_space(3))) void*)l, 16, 0, 0);
}

__device__ __forceinline__ float blockmax256(float m, float* red) {
#pragma unroll
  for (int off = 32; off; off >>= 1)
    m = fmaxf(m, __shfl_xor(m, off, 64));
  if ((threadIdx.x & 63) == 0) red[threadIdx.x >> 6] = m;
  __syncthreads();
  return fmaxf(fmaxf(red[0], red[1]), fmaxf(red[2], red[3]));
}

__device__ __forceinline__ int pack4(const float* v, float inv) {
  unsigned w = 0;
#pragma unroll
  for (int b = 0; b < 4; ++b) {
    int q = __float2int_rn(fmaxf(fminf(v[b] * inv, 127.f), -127.f));
    w |= ((unsigned)(unsigned char)(signed char)q) << (8 * b);
  }
  return (int)w;
}

// ---------------------------------------------------------------------------
// Kernel 1: W_full = dequant_int4 + CSR ortho -> per-row i8 quant + scale.
// ---------------------------------------------------------------------------
__global__ __launch_bounds__(256) void prep_w_i8(
    const int* __restrict__ bw, const float* __restrict__ scales,
    const float* __restrict__ vals, const int* __restrict__ cols,
    const int* __restrict__ rptr, signed char* __restrict__ Wq,
    float* __restrict__ sw) {
  __shared__ float row[IN_F];
  __shared__ float red[4];
  const int n = blockIdx.x;
  const int tid = threadIdx.x;
  const float s = scales[n];
  const int* bwr = bw + (size_t)n * (IN_F / 2);
#pragma unroll
  for (int it = 0; it < (IN_F / 2) / 256; ++it) {
    int j = it * 256 + tid;
    int p = bwr[j];
    int lo = p & 15;        lo = (lo >= 8) ? lo - 16 : lo;
    int hi = (p >> 4) & 15; hi = (hi >= 8) ? hi - 16 : hi;
    row[2 * j]     = (float)lo * s;
    row[2 * j + 1] = (float)hi * s;
  }
  __syncthreads();
  const int b = rptr[n], e = rptr[n + 1];
  for (int t = b + tid; t < e; t += 256)
    atomicAdd(&row[cols[t]], vals[t]);
  __syncthreads();
  float m = 0.f;
#pragma unroll
  for (int it = 0; it < IN_F / 256; ++it)
    m = fmaxf(m, fabsf(row[it * 256 + tid]));
  const float mm  = fmaxf(blockmax256(m, red), 1e-30f);
  const float inv = 127.f / mm;
  int4 w;
  w.x = pack4(&row[tid * 16 + 0],  inv);
  w.y = pack4(&row[tid * 16 + 4],  inv);
  w.z = pack4(&row[tid * 16 + 8],  inv);
  w.w = pack4(&row[tid * 16 + 12], inv);
  *(int4*)(Wq + (size_t)n * IN_F + tid * 16) = w;
  if (tid == 0) sw[n] = mm / 127.f;
}

// ---------------------------------------------------------------------------
// Kernel 2: X fp32 -> per-token i8 quant + scale.
// ---------------------------------------------------------------------------
__global__ __launch_bounds__(256) void cvt_x_i8(
    const float4* __restrict__ x, int* __restrict__ xq,
    float* __restrict__ sx) {
  __shared__ float red[4];
  const int tok = blockIdx.x;
  const int tid = threadIdx.x;
  const float4* xr = x + (size_t)tok * (IN_F / 4);
  float4 v[4];
  float m = 0.f;
#pragma unroll
  for (int j = 0; j < 4; ++j) {
    v[j] = xr[j * 256 + tid];
    m = fmaxf(m, fmaxf(fmaxf(fabsf(v[j].x), fabsf(v[j].y)),
                       fmaxf(fabsf(v[j].z), fabsf(v[j].w))));
  }
  const float mm  = fmaxf(blockmax256(m, red), 1e-30f);
  const float inv = 127.f / mm;
  int* xo = xq + (size_t)tok * (IN_F / 4);
#pragma unroll
  for (int j = 0; j < 4; ++j) {
    float vv[4] = {v[j].x, v[j].y, v[j].z, v[j].w};
    xo[j * 256 + tid] = pack4(vv, inv);
  }
  if (tid == 0) sx[tok] = mm / 127.f;
}

// ---------------------------------------------------------------------------
// Kernel 3: i8 GEMM, R7 sync skeleton AND R7 byte-exact LDS geometry.
//
// Per 256x128 operand tile = 32KB as two 16KB k-halves (h in {0,1}, 64
// i8-k each). Within a half (same bytes as R7's bf16 half):
//   byte(r, kb) = (r>>4)*1024 + (r&15)*64 + kb,  kb = k-byte 0..63
//   then byte ^= ((byte>>9)&1)<<5   (st_16x32 XOR swizzle)
// Staging: linear LDS dest (t*16), inverse-swizzled GLOBAL source -> 4
// lanes cover one contiguous 64B row segment (R7 coalescing: 16 rows x
// 64B per wave). Reader: laneoff = ((lane&15)<<6)|((lane>>4)<<4) ^ swz;
// frag(i) at (wr*8+i)*1024 + laneoff — byte-identical to R7 reads.
//
// Phases P1..P4 per K-tile, one barrier each; phase p's MFMA consumes
// fragments ds_read in phase p-1; staging 2 gloads/phase; vmcnt(2) at
// P2/P4 entries retires exactly the oldest 4 of 6 outstanding.
// ---------------------------------------------------------------------------
__global__ __launch_bounds__(512, 2) void gemm_i8(
    const unsigned char* __restrict__ A,   // [TOKENS][IN_F] i8
    const unsigned char* __restrict__ B,   // [OUT_F][IN_F] i8
    const float* __restrict__ sx,          // [TOKENS]
    const float* __restrict__ sw,          // [OUT_F]
    float* __restrict__ C) {               // [TOKENS][OUT_F] f32
  __shared__ __align__(16) char lds[131072];  // 2 buf x (A 32K + B 32K)

  const int nbn = OUT_F / BN;                  // 16
  const int cpx = ((TOKENS / BM) * nbn) >> 3;  // 64
  const int bid = blockIdx.x;
  const int swz = (bid & 7) * cpx + (bid >> 3);
  const int tm = swz / nbn, tn = swz % nbn;
  const long m0 = (long)tm * BM;
  const long n0 = (long)tn * BN;

  const int tid  = threadIdx.x;
  const int lane = tid & 63;
  const int wid  = tid >> 6;                // 0..7
  const int wr   = wid >> 2;                // 0..1
  const int wc   = wid & 3;                 // 0..3

  // ---- staging: linear LDS byte p -> logical (row, k-byte) (inverse swz)
  const int p0 = tid * 16;
  const int p1 = p0 + 8192;
  const int lin0 = p0 ^ (((p0 >> 9) & 1) << 5);
  const int lin1 = p1 ^ (((p1 >> 9) & 1) << 5);
  const int r0  = (((p0 >> 10) & 15) << 4) | ((lin0 >> 6) & 15);
  const int r1  = (((p1 >> 10) & 15) << 4) | ((lin1 >> 6) & 15);
  const int kb0 = lin0 & 63;
  const int kb1 = lin1 & 63;

  const unsigned char* Abase = A + m0 * IN_F;
  const unsigned char* Bbase = B + n0 * IN_F;

  // ---- reader lane offset (with XOR swizzle), R7-identical
  int laneoff = ((lane & 15) << 6) | ((lane >> 4) << 4);
  laneoff ^= ((laneoff >> 9) & 1) << 5;

#define STAGE_A(nb, kt, h)                                                     \
  do {                                                                         \
    gload_lds16(Abase + (size_t)r0 * IN_F + (kt) * 128 + (h) * 64 + kb0,       \
                lds + (nb) * 65536 + (h) * 16384 + p0);                        \
    gload_lds16(Abase + (size_t)r1 * IN_F + (kt) * 128 + (h) * 64 + kb1,       \
                lds + (nb) * 65536 + (h) * 16384 + p1);                        \
  } while (0)
#define STAGE_B(nb, kt, h)                                                     \
  do {                                                                         \
    gload_lds16(Bbase + (size_t)r0 * IN_F + (kt) * 128 + (h) * 64 + kb0,       \
                lds + (nb) * 65536 + 32768 + (h) * 16384 + p0);                \
    gload_lds16(Bbase + (size_t)r1 * IN_F + (kt) * 128 + (h) * 64 + kb1,       \
                lds + (nb) * 65536 + 32768 + (h) * 16384 + p1);                \
  } while (0)

  i32x4 acc[8][4];
#pragma unroll
  for (int i = 0; i < 8; ++i)
#pragma unroll
    for (int j = 0; j < 4; ++j) acc[i][j] = (i32x4)0;

  // fragment register sets (named, statically indexed — rule #20)
  i32x4 av1[4], av2[4], av3[4], av4[4], bv1[4], bv3[4];

  // ---- prologue: stage tile 0 into buf 0; preload s1(t0) after h0 resident
  STAGE_A(0, 0, 0);
  STAGE_B(0, 0, 0);
  STAGE_A(0, 0, 1);
  STAGE_B(0, 0, 1);
  VMCNT4();           // h0 of tile 0 resident (per-wave)
  BARRIER();
#pragma unroll
  for (int i = 0; i < 4; ++i)
    av1[i] = *(const i32x4*)(lds + (wr * 8 + i) * 1024 + laneoff);
#pragma unroll
  for (int j = 0; j < 4; ++j)
    bv1[j] = *(const i32x4*)(lds + 32768 + (wc * 4 + j) * 1024 + laneoff);

  for (int t = 0; t < NT; ++t) {
    const int b  = t & 1;
    const int nb = b ^ 1;
    const char* bufA  = lds + b * 65536;
    const char* bufB  = bufA + 32768;
    const char* nbufA = lds + nb * 65536;
    const char* nbufB = nbufA + 32768;
    const bool pf = (t + 1 < NT);

    // ===== P1: MFMA s1 (av1,bv1: rows lo, h0) | load av2 | stage A-h0(t+1)
    BARRIER();
    __builtin_amdgcn_s_setprio(1);
    if (pf) STAGE_A(nb, t + 1, 0);
#pragma unroll
    for (int i = 0; i < 4; ++i)
      av2[i] = *(const i32x4*)(bufA + (wr * 8 + 4 + i) * 1024 + laneoff);
#pragma unroll
    for (int i = 0; i < 4; ++i)
#pragma unroll
      for (int j = 0; j < 4; ++j)
        acc[i][j] = __builtin_amdgcn_mfma_i32_16x16x64_i8(av1[i], bv1[j], acc[i][j], 0, 0, 0);
    __builtin_amdgcn_s_setprio(0);

    // ===== P2: MFMA s2 (av2,bv1) | load av3,bv3 (h1) | stage B-h0(t+1)
    if (pf) { VMCNT2(); } else { VMCNT0(); }  // A-h1(t), B-h1(t) resident
    BARRIER();
    __builtin_amdgcn_s_setprio(1);
    if (pf) STAGE_B(nb, t + 1, 0);
#pragma unroll
    for (int i = 0; i < 4; ++i)
      av3[i] = *(const i32x4*)(bufA + 16384 + (wr * 8 + i) * 1024 + laneoff);
#pragma unroll
    for (int j = 0; j < 4; ++j)
      bv3[j] = *(const i32x4*)(bufB + 16384 + (wc * 4 + j) * 1024 + laneoff);
#pragma unroll
    for (int i = 0; i < 4; ++i)
#pragma unroll
      for (int j = 0; j < 4; ++j)
        acc[4 + i][j] = __builtin_amdgcn_mfma_i32_16x16x64_i8(av2[i], bv1[j], acc[4 + i][j], 0, 0, 0);
    __builtin_amdgcn_s_setprio(0);

    // ===== P3: MFMA s3 (av3,bv3: rows lo, h1) | load av4 | stage A-h1(t+1)
    BARRIER();
    __builtin_amdgcn_s_setprio(1);
    if (pf) STAGE_A(nb, t + 1, 1);
#pragma unroll
    for (int i = 0; i < 4; ++i)
      av4[i] = *(const i32x4*)(bufA + 16384 + (wr * 8 + 4 + i) * 1024 + laneoff);
#pragma unroll
    for (int i = 0; i < 4; ++i)
#pragma unroll
      for (int j = 0; j < 4; ++j)
        acc[i][j] = __builtin_amdgcn_mfma_i32_16x16x64_i8(av3[i], bv3[j], acc[i][j], 0, 0, 0);
    __builtin_amdgcn_s_setprio(0);

    // ===== P4: MFMA s4 (av4,bv3) | load s1(t+1) from buf nb | stage B-h1(t+1)
    if (pf) { VMCNT2(); } else { VMCNT0(); }  // A-h0(t+1), B-h0(t+1) resident
    BARRIER();
    __builtin_amdgcn_s_setprio(1);
    if (pf) {
      STAGE_B(nb, t + 1, 1);
#pragma unroll
      for (int i = 0; i < 4; ++i)
        av1[i] = *(const i32x4*)(nbufA + (wr * 8 + i) * 1024 + laneoff);
#pragma unroll
      for (int j = 0; j < 4; ++j)
        bv1[j] = *(const i32x4*)(nbufB + (wc * 4 + j) * 1024 + laneoff);
    }
#pragma unroll
    for (int i = 0; i < 4; ++i)
#pragma unroll
      for (int j = 0; j < 4; ++j)
        acc[4 + i][j] = __builtin_amdgcn_mfma_i32_16x16x64_i8(av4[i], bv3[j], acc[4 + i][j], 0, 0, 0);
    __builtin_amdgcn_s_setprio(0);
  }
#undef STAGE_A
#undef STAGE_B

  // ---- epilogue: C = i32acc * sx[row] * sw[col]
  const int er = (lane >> 4) * 4;
  const int ec = lane & 15;
#pragma unroll
  for (int i = 0; i < 8; ++i) {
    long rbase = m0 + wr * 128 + i * 16 + er;
    float sxq[4];
#pragma unroll
    for (int q = 0; q < 4; ++q) sxq[q] = sx[rbase + q];
#pragma unroll
    for (int j = 0; j < 4; ++j) {
      long cbase = n0 + wc * 64 + j * 16 + ec;
      const float swc = sw[cbase];
#pragma unroll
      for (int q = 0; q < 4; ++q)
        C[(rbase + q) * OUT_F + cbase] = (float)acc[i][j][q] * sxq[q] * swc;
    }
  }
}

// ---------------------------------------------------------------------------
// Fallback (ws too small): slow but correct fp32 path.
// ---------------------------------------------------------------------------
__global__ __launch_bounds__(256) void fallback_kernel(
    const float* __restrict__ x, const int* __restrict__ bw,
    const float* __restrict__ scales, const float* __restrict__ vals,
    const int* __restrict__ cols, const int* __restrict__ rptr,
    float* __restrict__ out) {
  const int oc  = blockIdx.x * 64 + (threadIdx.x & 63);
  const int tok = blockIdx.y * 4 + (threadIdx.x >> 6);
  const float s = scales[oc];
  const int* bwr = bw + (size_t)oc * (IN_F / 2);
  const float* xr = x + (size_t)tok * IN_F;
  float acc = 0.f;
  for (int j = 0; j < IN_F / 2; ++j) {
    int p = bwr[j];
    int lo = p & 15;        lo = (lo >= 8) ? lo - 16 : lo;
    int hi = (p >> 4) & 15; hi = (hi >= 8) ? hi - 16 : hi;
    acc += ((float)lo * s) * xr[2 * j] + ((float)hi * s) * xr[2 * j + 1];
  }
  const int b = rptr[oc], e = rptr[oc + 1];
  for (int t = b; t < e; ++t) acc += vals[t] * xr[cols[t]];
  out[(size_t)tok * OUT_F + oc] = acc;
}

extern "C" void kernel_launch(void* const* d_in, const int* in_sizes, int n_in,
                              void* d_out, int out_size, void* d_ws, size_t ws_size,
                              hipStream_t stream) {
  const float* x      = (const float*)d_in[0];
  const int*   bw     = (const int*)d_in[1];
  const float* scales = (const float*)d_in[2];
  const float* vals   = (const float*)d_in[3];
  const int*   cols   = (const int*)d_in[4];
  const int*   rptr   = (const int*)d_in[5];
  float* out = (float*)d_out;

  // workspace: Wq 16MB | Xq 32MB | sw 16KB | sx 32KB
  const size_t wq_off = 0;
  const size_t xq_off = (size_t)OUT_F * IN_F;            // 16 MB
  const size_t sw_off = xq_off + (size_t)TOKENS * IN_F;  // 48 MB
  const size_t sx_off = sw_off + 65536;
  const size_t need   = sx_off + 65536;

  if (ws_size >= need) {
    signed char* Wq = (signed char*)d_ws + wq_off;
    signed char* Xq = (signed char*)d_ws + xq_off;
    float* sw = (float*)((char*)d_ws + sw_off);
    float* sx = (float*)((char*)d_ws + sx_off);
    prep_w_i8<<<OUT_F, 256, 0, stream>>>(bw, scales, vals, cols, rptr, Wq, sw);
    cvt_x_i8<<<TOKENS, 256, 0, stream>>>((const float4*)x, (int*)Xq, sx);
    gemm_i8<<<(TOKENS / BM) * (OUT_F / BN), 512, 0, stream>>>(
        (const unsigned char*)Xq, (const unsigned char*)Wq, sx, sw, out);
  } else {
    dim3 grid(OUT_F / 64, TOKENS / 4);
    fallback_kernel<<<grid, 256, 0, stream>>>(x, bw, scales, vals, cols, rptr, out);
  }
}